// Round 10
// baseline (353.360 us; speedup 1.0000x reference)
//
#include <hip/hip_runtime.h>
#include <hip/hip_bf16.h>
#include <math.h>

typedef __bf16 bf16;
typedef bf16 bf16x8 __attribute__((ext_vector_type(8)));
typedef bf16 bf16x4 __attribute__((ext_vector_type(4)));
typedef float f32x2 __attribute__((ext_vector_type(2)));
typedef float f32x4 __attribute__((ext_vector_type(4)));
typedef float f32x16 __attribute__((ext_vector_type(16)));

#define MFMA16(a, b, c) __builtin_amdgcn_mfma_f32_16x16x32_bf16(a, b, c, 0, 0, 0)
#define MFMA32(a, b, c) __builtin_amdgcn_mfma_f32_32x32x16_bf16(a, b, c, 0, 0, 0)
#define LOG2E 1.4426950408889634f
#define NEG_SHIFT -40.0f  // fixed softmax shift (base-2); cancels in O/l

__device__ __forceinline__ void glds16(const bf16* g, bf16* l) {
  __builtin_amdgcn_global_load_lds(
      (const __attribute__((address_space(1))) void*)g,
      (__attribute__((address_space(3))) void*)l, 16, 0, 0);
}

__device__ inline unsigned pkbf(float a, float b) {
  union { bf16 h; unsigned short u; } ca, cb;
  ca.h = (bf16)a;
  cb.h = (bf16)b;
  return (unsigned)ca.u | ((unsigned)cb.u << 16);
}

// v_permlane32_swap_b32: one swap yields BOTH P fragments across lane halves.
__device__ __forceinline__ void pl32swap(unsigned& a, unsigned& b) {
  asm("v_permlane32_swap_b32 %0, %1" : "+v"(a), "+v"(b));
}

// 32-float bias window -> f32x16 (single vector construction; loads can land
// directly in the destination registers -- no element movs).
__device__ __forceinline__ f32x16 ld_bias16(const float4* __restrict__ p) {
  float4 a = p[0], b = p[8], c = p[16], d = p[24];
  return (f32x16){a.x, a.y, a.z, a.w, b.x, b.y, b.z, b.w,
                  c.x, c.y, c.z, c.w, d.x, d.y, d.z, d.w};
}

// T5 bucket bias at window index x (= 2047 + rel), raw (unscaled).
__device__ inline float t5bias(const float* __restrict__ table, int h, int x) {
  if (x > 4094) return 0.f;  // pad slot
  int rel = x - 2047;
  int bucket = (rel > 0) ? 16 : 0;
  int ar = rel < 0 ? -rel : rel;
  int v;
  if (ar < 8) {
    v = ar;
  } else {
    double tt = log((double)ar / 8.0) / log(16.0) * 8.0;
    int lg = 8 + (int)tt;
    v = lg < 15 ? lg : 15;
  }
  return table[(bucket + v) * 8 + h];
}

// ---------------------------------------------------------------------------
// prep: [0,4096) rms+ln -> normed bf16 | [4096,4224) raw lut + remain |
//       [4224,5248) wt transpose | [5248,5376) lutq float4, PRE-SCALED:
//       lutq = LOG2E*bias + NEG_SHIFT (folded exp2 argument)
// ---------------------------------------------------------------------------
__global__ __launch_bounds__(256) void prep_kernel(
    const float* __restrict__ hidden, const float* __restrict__ ln_w,
    const float* __restrict__ wq, const float* __restrict__ wk,
    const float* __restrict__ wv, const float* __restrict__ wo,
    const float* __restrict__ table, bf16* __restrict__ normed,
    float* __restrict__ lut, float4* __restrict__ lutq,
    float* __restrict__ out_remain, bf16* __restrict__ wt_qkv,
    bf16* __restrict__ wt_o) {
  __shared__ float tile[32][33];
  int bid = blockIdx.x;
  int t = threadIdx.x;
  if (bid < 4096) {
    int row = bid * 4 + (t >> 6);
    int lane = t & 63;
    const float4* xr = (const float4*)(hidden + (size_t)row * 512);
    float4 a = xr[lane];
    float4 b = xr[lane + 64];
    float s = a.x * a.x + a.y * a.y + a.z * a.z + a.w * a.w +
              b.x * b.x + b.y * b.y + b.z * b.z + b.w * b.w;
#pragma unroll
    for (int off = 32; off > 0; off >>= 1) s += __shfl_down(s, off, 64);
    float tot = __shfl(s, 0, 64);
    float rscale = rsqrtf(tot * (1.0f / 512.0f) + 1e-6f);
    float4 w0 = *(const float4*)(ln_w + 4 * lane);
    float4 w1 = *(const float4*)(ln_w + 256 + 4 * lane);
    bf16x4 o0, o1;
    o0[0] = (bf16)(a.x * rscale * w0.x);
    o0[1] = (bf16)(a.y * rscale * w0.y);
    o0[2] = (bf16)(a.z * rscale * w0.z);
    o0[3] = (bf16)(a.w * rscale * w0.w);
    o1[0] = (bf16)(b.x * rscale * w1.x);
    o1[1] = (bf16)(b.y * rscale * w1.y);
    o1[2] = (bf16)(b.z * rscale * w1.z);
    o1[3] = (bf16)(b.w * rscale * w1.w);
    *(bf16x4*)(normed + (size_t)row * 512 + 4 * lane) = o0;
    *(bf16x4*)(normed + (size_t)row * 512 + 256 + 4 * lane) = o1;
  } else if (bid < 4224) {
    int i = (bid - 4096) * 256 + t;  // 8 * 4096
    int h = i >> 12;
    int d = i & 4095;
    lut[(size_t)h * 4096 + d] = t5bias(table, h, d);
    if (i < 8) out_remain[i] = (float)i;
  } else if (bid < 5248) {
    int bid2 = bid - 4224;
    int mat = bid2 >> 8;
    int rem = bid2 & 255;
    int e0 = (rem & 15) * 32;
    int k0 = (rem >> 4) * 32;
    int tx = t & 31, ty = t >> 5;
    const float* W = (mat == 0) ? wq : (mat == 1) ? wk : (mat == 2) ? wv : wo;
#pragma unroll
    for (int j = 0; j < 32; j += 8)
      tile[ty + j][tx] = W[(size_t)(k0 + ty + j) * 512 + e0 + tx];
    __syncthreads();
    bf16* dst = (mat < 3) ? (wt_qkv + (size_t)mat * 512 * 512) : wt_o;
#pragma unroll
    for (int j = 0; j < 32; j += 8)
      dst[(size_t)(e0 + ty + j) * 512 + k0 + tx] = (bf16)tile[tx][ty + j];
  } else {
    int i = (bid - 5248) * 256 + t;  // 8 * 4096
    int h = i >> 12;
    int d = i & 4095;
    float4 o;
    o.x = t5bias(table, h, d) * LOG2E + NEG_SHIFT;
    o.y = t5bias(table, h, d + 1) * LOG2E + NEG_SHIFT;
    o.z = t5bias(table, h, d + 2) * LOG2E + NEG_SHIFT;
    o.w = t5bias(table, h, d + 3) * LOG2E + NEG_SHIFT;
    lutq[(size_t)h * 4096 + d] = o;
  }
}

// ---------------------------------------------------------------------------
// qkv GEMM: R0-proven single-buffer glds staging ([128][32] tiles).
// Q is PRE-SCALED by LOG2E at store (folds the softmax fmaf into the GEMM).
// ---------------------------------------------------------------------------
__global__ __launch_bounds__(256) void qkv_gemm(
    const bf16* __restrict__ normed, const bf16* __restrict__ wt,
    bf16* __restrict__ qb, bf16* __restrict__ kb, bf16* __restrict__ vtb) {
  __shared__ __align__(16) char smem[19456];
  bf16* As = (bf16*)smem;           // [128][32]
  bf16* Bs = (bf16*)(smem + 8192);  // [128][32]
  int t = threadIdx.x;
  int wave = t >> 6, lane = t & 63;
  int quad = lane >> 4, lc = lane & 15;
  int wm = wave >> 1, wn = wave & 1;
  int m0 = blockIdx.x * 128, n0 = blockIdx.y * 128;

  f32x4 acc[4][4];
#pragma unroll
  for (int i = 0; i < 4; i++)
#pragma unroll
    for (int j = 0; j < 4; j++) acc[i][j] = (f32x4){0.f, 0.f, 0.f, 0.f};

  int rw = lane >> 2;        // 0..15
  int c8 = (lane & 3) * 8;   // element col within 32
  const bf16* gA = normed + (size_t)(m0 + wave * 32 + rw) * 512 + c8;
  const bf16* gB = wt + (size_t)(n0 + wave * 32 + rw) * 512 + c8;
  bf16* lA = As + wave * 1024;  // wave-uniform LDS base
  bf16* lB = Bs + wave * 1024;

  for (int kt = 0; kt < 16; ++kt) {
    int k0 = kt * 32;
    __syncthreads();  // prev iter's frag reads done before overwrite
    glds16(gA + k0, lA);
    glds16(gA + 16 * 512 + k0, lA + 512);
    glds16(gB + k0, lB);
    glds16(gB + 16 * 512 + k0, lB + 512);
    __syncthreads();  // vmcnt(0) drain + barrier
    bf16x8 af[4], bfr[4];
#pragma unroll
    for (int i = 0; i < 4; i++)
      af[i] = *(const bf16x8*)&As[(wm * 64 + i * 16 + lc) * 32 + quad * 8];
#pragma unroll
    for (int j = 0; j < 4; j++)
      bfr[j] = *(const bf16x8*)&Bs[(wn * 64 + j * 16 + lc) * 32 + quad * 8];
#pragma unroll
    for (int i = 0; i < 4; i++)
#pragma unroll
      for (int j = 0; j < 4; j++)
        acc[i][j] = MFMA16(af[i], bfr[j], acc[i][j]);
  }

  __syncthreads();  // all frag reads done before LDS reuse / epilogue
  int mat = n0 >> 9;
  int e_base = (n0 & 511) + wn * 64;
  int hh = e_base >> 6;
  int grow0 = m0 + wm * 64;
  int nbi = grow0 >> 11, sbase = grow0 & 2047;

  if (mat == 2) {
    // V: direct transposed stores vt[bh][d][s] (8B per store)
    bf16* dv = vtb + ((size_t)(nbi * 8 + hh) * 64) * 2048;
#pragma unroll
    for (int i = 0; i < 4; i++) {
      int s = sbase + i * 16 + quad * 4;
#pragma unroll
      for (int j = 0; j < 4; j++) {
        int d = j * 16 + lc;
        bf16x4 o4;
#pragma unroll
        for (int r = 0; r < 4; r++) o4[r] = (bf16)acc[i][j][r];
        *(bf16x4*)(dv + (size_t)d * 2048 + s) = o4;
      }
    }
  } else {
    float qsc = (mat == 0) ? LOG2E : 1.0f;  // pre-scale Q for exp2 softmax
    bf16* dst0 = (mat == 0) ? qb : kb;
    bf16* dst = dst0 + (((size_t)nbi * 8 + hh) * 2048 + sbase) * 64;
    bf16* Cw = (bf16*)smem + wave * 2432;  // 32x76 per wave
#pragma unroll
    for (int p = 0; p < 2; ++p) {
#pragma unroll
      for (int i2 = 0; i2 < 2; ++i2) {
#pragma unroll
        for (int j = 0; j < 4; ++j)
#pragma unroll
          for (int r = 0; r < 4; ++r)
            Cw[(i2 * 16 + quad * 4 + r) * 76 + j * 16 + lc] =
                (bf16)(acc[2 * p + i2][j][r] * qsc);
      }
      // wave-local write->read; compiler inserts lgkmcnt wait
#pragma unroll
      for (int c = 0; c < 4; ++c) {
        bf16x8 vch =
            *(const bf16x8*)&Cw[(c * 8 + (lane >> 3)) * 76 + (lane & 7) * 8];
        *(bf16x8*)(dst + (size_t)(p * 32 + c * 8 + (lane >> 3)) * 64 +
                   (lane & 7) * 8) = vch;
      }
    }
  }
}

// ---------------------------------------------------------------------------
// attn: blocks [0,1024) = flash attention; [1024,33792) = bias.
// R9 core + T15 double-pipeline: QK0,QK1 issued back-to-back, then
// exp0 runs while st1's MFMAs execute, exp1 runs while PV0's MFMAs execute.
// ---------------------------------------------------------------------------
__global__ __launch_bounds__(256, 3) void attn_kernel(
    const bf16* __restrict__ qg, const bf16* __restrict__ kg,
    const bf16* __restrict__ vtg, const float4* __restrict__ lutq,
    const float* __restrict__ lut, bf16* __restrict__ ctx,
    float* __restrict__ bias_out) {
  __shared__ bf16 Ks[2][64][72];  // 2 x 9216 B, double-buffered
  __shared__ bf16 Vs[2][64][72];
  int t = threadIdx.x;

  if (blockIdx.x >= 1024) {  // ---- bias path (R0-proven) ----
    size_t i = (((size_t)blockIdx.x - 1024) * 256 + t) * 4;
    int h = (int)(i >> 22);
    int q = (int)((i >> 11) & 2047);
    int k = (int)(i & 2047);
    const float* lh = lut + (size_t)h * 4096 + (2047 - q);
    float4 v = {lh[k], lh[k + 1], lh[k + 2], lh[k + 3]};
    *(float4*)(bias_out + i) = v;
    return;
  }

  // ---- attention path ----
  int id = blockIdx.x;
  int xcd = id & 7, slot = id >> 3;  // XCD-aware: each XCD owns 8 whole bh
  int bh = xcd * 8 + (slot >> 4);
  int qt = slot & 15;
  int n = bh >> 3, h = bh & 7;
  int q0 = qt * 128;

  int wave = t >> 6, lane = t & 63;
  int l31 = lane & 31, hi = lane >> 5;
  int q = q0 + wave * 32 + l31;

  // bias base for this lane (lutq is pre-scaled: LOG2E*bias + NEG_SHIFT)
  const float4* bp = lutq + (size_t)h * 4096 + (2047 + 4 * hi - q);

  // Q fragments: B[k=d][n=q], pre-scaled by LOG2E (L2-hot)
  const bf16* qp = qg + ((size_t)bh * 2048 + q) * 64;
  bf16x8 Qf[4];
#pragma unroll
  for (int c = 0; c < 4; c++) Qf[c] = *(const bf16x8*)(qp + c * 16 + hi * 8);

  f32x16 O[2];
#pragma unroll
  for (int i = 0; i < 2; i++)
#pragma unroll
    for (int e = 0; e < 16; e++) O[i][e] = 0.f;
  f32x2 lsA = {0.f, 0.f}, lsB = {0.f, 0.f};

  int srow = t >> 2, scol = (t & 3) * 16;
  const bf16* kp = kg + (size_t)bh * 2048 * 64 + (size_t)srow * 64 + scol;
  const bf16* vp = vtg + (size_t)bh * 64 * 2048 + (size_t)srow * 2048 + scol;

  // prologue: stage tile 0 -> buf 0
  {
    bf16x8 a0 = *(const bf16x8*)(kp);
    bf16x8 a1 = *(const bf16x8*)(kp + 8);
    bf16x8 a2 = *(const bf16x8*)(vp);
    bf16x8 a3 = *(const bf16x8*)(vp + 8);
    *(bf16x8*)&Ks[0][srow][scol] = a0;
    *(bf16x8*)&Ks[0][srow][scol + 8] = a1;
    *(bf16x8*)&Vs[0][srow][scol] = a2;
    *(bf16x8*)&Vs[0][srow][scol + 8] = a3;
  }
  // bias tile 0 -> st (MFMA C-operand)
  f32x16 st[2];
  st[0] = ld_bias16(bp);
  st[1] = ld_bias16(bp + 32);
  const float4* bpn = bp + 64;
  __syncthreads();

#pragma unroll 1
  for (int kt = 0; kt < 32; ++kt) {
    int RB = kt & 1;
    bool pf = (kt < 31);
    bf16x8 kv0, kv1, vv0, vv1;
    if (pf) {  // prefetch next K/V tile into registers
      const bf16* kn = kp + (size_t)(kt + 1) * 4096;
      const bf16* vn = vp + (kt + 1) * 64;
      kv0 = *(const bf16x8*)(kn);
      kv1 = *(const bf16x8*)(kn + 8);
      vv0 = *(const bf16x8*)(vn);
      vv1 = *(const bf16x8*)(vn + 8);
    }

    // ---- Phase 1: QK for BOTH mi (back-to-back MFMA issue) ----
    {
      const bf16* kr0 = &Ks[RB][l31][hi * 8];
      bf16x8 a0 = *(const bf16x8*)(kr0);
      bf16x8 a1 = *(const bf16x8*)(kr0 + 16);
      bf16x8 a2 = *(const bf16x8*)(kr0 + 32);
      bf16x8 a3 = *(const bf16x8*)(kr0 + 48);
      __builtin_amdgcn_s_setprio(1);
      st[0] = MFMA32(a0, Qf[0], st[0]);
      st[0] = MFMA32(a1, Qf[1], st[0]);
      st[0] = MFMA32(a2, Qf[2], st[0]);
      st[0] = MFMA32(a3, Qf[3], st[0]);
      __builtin_amdgcn_s_setprio(0);
      const bf16* kr1 = &Ks[RB][32 + l31][hi * 8];
      bf16x8 b0 = *(const bf16x8*)(kr1);
      bf16x8 b1 = *(const bf16x8*)(kr1 + 16);
      bf16x8 b2 = *(const bf16x8*)(kr1 + 32);
      bf16x8 b3 = *(const bf16x8*)(kr1 + 48);
      __builtin_amdgcn_s_setprio(1);
      st[1] = MFMA32(b0, Qf[0], st[1]);
      st[1] = MFMA32(b1, Qf[1], st[1]);
      st[1] = MFMA32(b2, Qf[2], st[1]);
      st[1] = MFMA32(b3, Qf[3], st[1]);
      __builtin_amdgcn_s_setprio(0);
    }

    // ---- Phases 2-5: softmax(mi) then PV(mi); exp(1) overlaps PV(0) ----
#pragma unroll
    for (int mi = 0; mi < 2; mi++) {
      unsigned D[8];
#pragma unroll
      for (int g = 0; g < 4; g++) {
#pragma unroll
        for (int e = 0; e < 4; e++)
          st[mi][4 * g + e] = __builtin_amdgcn_exp2f(st[mi][4 * g + e]);
        lsA += (f32x2){st[mi][4 * g + 0], st[mi][4 * g + 1]};
        lsB += (f32x2){st[mi][4 * g + 2], st[mi][4 * g + 3]};
        D[2 * g] = pkbf(st[mi][4 * g + 0], st[mi][4 * g + 1]);
        D[2 * g + 1] = pkbf(st[mi][4 * g + 2], st[mi][4 * g + 3]);
      }
      if (pf) {  // st[mi] dead after pack: reload next tile's bias
        st[mi] = ld_bias16(bpn + mi * 32);
      }
      pl32swap(D[0], D[2]);
      pl32swap(D[1], D[3]);
      pl32swap(D[4], D[6]);
      pl32swap(D[5], D[7]);
      union { uint4 u; bf16x8 v; } cv0, cv1;
      cv0.u = make_uint4(D[0], D[1], D[2], D[3]);
      cv1.u = make_uint4(D[4], D[5], D[6], D[7]);
#pragma unroll
      for (int kk = 0; kk < 2; kk++) {
        int kc = 2 * mi + kk;
        const bf16* vrow = &Vs[RB][l31][kc * 16 + hi * 8];
        bf16x8 vf0 = *(const bf16x8*)(vrow);
        bf16x8 vf1 = *(const bf16x8*)(vrow + 32 * 72);
        bf16x8 pfv = kk ? cv1.v : cv0.v;
        __builtin_amdgcn_s_setprio(1);
        O[0] = MFMA32(vf0, pfv, O[0]);
        O[1] = MFMA32(vf1, pfv, O[1]);
        __builtin_amdgcn_s_setprio(0);
      }
    }

    if (pf) {
      int WB = RB ^ 1;
      *(bf16x8*)&Ks[WB][srow][scol] = kv0;
      *(bf16x8*)&Ks[WB][srow][scol + 8] = kv1;
      *(bf16x8*)&Vs[WB][srow][scol] = vv0;
      *(bf16x8*)&Vs[WB][srow][scol + 8] = vv1;
      bpn += 64;
    }
    __syncthreads();
  }

  float l_run = lsA.x + lsA.y + lsB.x + lsB.y;
  l_run += __shfl_xor(l_run, 32, 64);
  float inv = 1.0f / l_run;
  bf16* cp = ctx + ((size_t)n * 2048 + q) * 512 + h * 64;
#pragma unroll
  for (int md = 0; md < 2; md++)
#pragma unroll
    for (int g = 0; g < 4; g++) {
      bf16x4 o4;
#pragma unroll
      for (int e = 0; e < 4; e++) o4[e] = (bf16)(O[md][4 * g + e] * inv);
      *(bf16x4*)(cp + md * 32 + 8 * g + hi * 4) = o4;
    }
}

// ---------------------------------------------------------------------------
// oproj: out = ctx @ wo + hidden (residual), fp32 out. R0-proven single-
// buffer glds staging.
// ---------------------------------------------------------------------------
__global__ __launch_bounds__(256) void oproj_gemm(
    const bf16* __restrict__ ctx, const bf16* __restrict__ wt_o,
    const float* __restrict__ hidden, float* __restrict__ out) {
  __shared__ __align__(16) char smem[16384];
  bf16* As = (bf16*)smem;
  bf16* Bs = (bf16*)(smem + 8192);
  int t = threadIdx.x;
  int wave = t >> 6, lane = t & 63;
  int quad = lane >> 4, lc = lane & 15;
  int wm = wave >> 1, wn = wave & 1;
  int m0 = blockIdx.x * 128, n0 = blockIdx.y * 128;

  f32x4 acc[4][4];
#pragma unroll
  for (int i = 0; i < 4; i++)
#pragma unroll
    for (int j = 0; j < 4; j++) acc[i][j] = (f32x4){0.f, 0.f, 0.f, 0.f};

  int rw = lane >> 2;
  int c8 = (lane & 3) * 8;
  const bf16* gA = ctx + (size_t)(m0 + wave * 32 + rw) * 512 + c8;
  const bf16* gB = wt_o + (size_t)(n0 + wave * 32 + rw) * 512 + c8;
  bf16* lA = As + wave * 1024;
  bf16* lB = Bs + wave * 1024;

  for (int kt = 0; kt < 16; ++kt) {
    int k0 = kt * 32;
    __syncthreads();
    glds16(gA + k0, lA);
    glds16(gA + 16 * 512 + k0, lA + 512);
    glds16(gB + k0, lB);
    glds16(gB + 16 * 512 + k0, lB + 512);
    __syncthreads();
    bf16x8 af[4], bfr[4];
#pragma unroll
    for (int i = 0; i < 4; i++)
      af[i] = *(const bf16x8*)&As[(wm * 64 + i * 16 + lc) * 32 + quad * 8];
#pragma unroll
    for (int j = 0; j < 4; j++)
      bfr[j] = *(const bf16x8*)&Bs[(wn * 64 + j * 16 + lc) * 32 + quad * 8];
#pragma unroll
    for (int i = 0; i < 4; i++)
#pragma unroll
      for (int j = 0; j < 4; j++)
        acc[i][j] = MFMA16(af[i], bfr[j], acc[i][j]);
  }

#pragma unroll
  for (int i = 0; i < 4; i++) {
#pragma unroll
    for (int j = 0; j < 4; j++) {
#pragma unroll
      for (int r = 0; r < 4; r++) {
        int grow = m0 + wm * 64 + i * 16 + quad * 4 + r;
        int gcol = n0 + wn * 64 + j * 16 + lc;
        size_t idx = (size_t)grow * 512 + gcol;
        out[idx] = acc[i][j][r] + hidden[idx];
      }
    }
  }
}

// ---------------------------------------------------------------------------
extern "C" void kernel_launch(void* const* d_in, const int* in_sizes, int n_in,
                              void* d_out, int out_size, void* d_ws, size_t ws_size,
                              hipStream_t stream) {
  const float* hidden = (const float*)d_in[0];
  const float* ln_w = (const float*)d_in[1];
  const float* wq = (const float*)d_in[2];
  const float* wk = (const float*)d_in[3];
  const float* wv = (const float*)d_in[4];
  const float* wo = (const float*)d_in[5];
  const float* table = (const float*)d_in[6];

  float* out_hidden = (float*)d_out;                       // 8*2048*512
  float* out_bias = out_hidden + (size_t)8 * 2048 * 512;   // 8*2048*2048
  float* out_remain = out_bias + (size_t)8 * 2048 * 2048;  // 8

  char* ws = (char*)d_ws;
  bf16* normed = (bf16*)(ws + 0);            // 16 MiB (reused as ctx later)
  float* lut = (float*)(ws + 16777216);      // 128 KiB
  float4* lutq = (float4*)(ws + 16908288);   // 512 KiB
  bf16* wt_qkv = (bf16*)(ws + 17432576);     // 1.5 MiB
  bf16* wt_o = (bf16*)(ws + 19005440);       // 0.5 MiB
  bf16* qb = (bf16*)(ws + 19529728);         // 16 MiB each
  bf16* kb = qb + (size_t)8 * 8 * 2048 * 64;
  bf16* vtb = kb + (size_t)8 * 8 * 2048 * 64;
  bf16* ctx = normed;  // alias: normed consumed by qkv before attn writes ctx

  prep_kernel<<<dim3(5376), dim3(256), 0, stream>>>(
      hidden, ln_w, wq, wk, wv, wo, table, normed, lut, lutq, out_remain,
      wt_qkv, wt_o);
  qkv_gemm<<<dim3(128, 12), dim3(256), 0, stream>>>(normed, wt_qkv, qb, kb, vtb);
  attn_kernel<<<dim3(1024 + 32768), dim3(256), 0, stream>>>(
      qb, kb, vtb, lutq, lut, ctx, out_bias);
  oproj_gemm<<<dim3(128, 4), dim3(256), 0, stream>>>(ctx, wt_o, hidden,
                                                     out_hidden);
}

// Round 11
// 346.942 us; speedup vs baseline: 1.0185x; 1.0185x over previous
//
#include <hip/hip_runtime.h>
#include <hip/hip_bf16.h>
#include <math.h>

typedef __bf16 bf16;
typedef bf16 bf16x8 __attribute__((ext_vector_type(8)));
typedef bf16 bf16x4 __attribute__((ext_vector_type(4)));
typedef float f32x2 __attribute__((ext_vector_type(2)));
typedef float f32x4 __attribute__((ext_vector_type(4)));
typedef float f32x16 __attribute__((ext_vector_type(16)));

#define MFMA16(a, b, c) __builtin_amdgcn_mfma_f32_16x16x32_bf16(a, b, c, 0, 0, 0)
#define MFMA32(a, b, c) __builtin_amdgcn_mfma_f32_32x32x16_bf16(a, b, c, 0, 0, 0)
#define LOG2E 1.4426950408889634f
#define NEG_SHIFT -40.0f  // fixed softmax shift (base-2); cancels in O/l

__device__ __forceinline__ void glds16(const bf16* g, bf16* l) {
  __builtin_amdgcn_global_load_lds(
      (const __attribute__((address_space(1))) void*)g,
      (__attribute__((address_space(3))) void*)l, 16, 0, 0);
}

__device__ inline unsigned pkbf(float a, float b) {
  union { bf16 h; unsigned short u; } ca, cb;
  ca.h = (bf16)a;
  cb.h = (bf16)b;
  return (unsigned)ca.u | ((unsigned)cb.u << 16);
}

// v_permlane32_swap_b32: one swap yields BOTH P fragments across lane halves.
__device__ __forceinline__ void pl32swap(unsigned& a, unsigned& b) {
  asm("v_permlane32_swap_b32 %0, %1" : "+v"(a), "+v"(b));
}

// T5 bucket bias at window index x (= 2047 + rel), raw (unscaled).
__device__ inline float t5bias(const float* __restrict__ table, int h, int x) {
  if (x > 4094) return 0.f;  // pad slot
  int rel = x - 2047;
  int bucket = (rel > 0) ? 16 : 0;
  int ar = rel < 0 ? -rel : rel;
  int v;
  if (ar < 8) {
    v = ar;
  } else {
    double tt = log((double)ar / 8.0) / log(16.0) * 8.0;
    int lg = 8 + (int)tt;
    v = lg < 15 ? lg : 15;
  }
  return table[(bucket + v) * 8 + h];
}

// ---------------------------------------------------------------------------
// prep: [0,4096) rms+ln -> normed bf16 | [4096,4224) raw lut + remain |
//       [4224,5248) wt transpose | [5248,5376) lutq float4, PRE-SCALED:
//       lutq = LOG2E*bias + NEG_SHIFT (folded exp2 argument)
// ---------------------------------------------------------------------------
__global__ __launch_bounds__(256) void prep_kernel(
    const float* __restrict__ hidden, const float* __restrict__ ln_w,
    const float* __restrict__ wq, const float* __restrict__ wk,
    const float* __restrict__ wv, const float* __restrict__ wo,
    const float* __restrict__ table, bf16* __restrict__ normed,
    float* __restrict__ lut, float4* __restrict__ lutq,
    float* __restrict__ out_remain, bf16* __restrict__ wt_qkv,
    bf16* __restrict__ wt_o) {
  __shared__ float tile[32][33];
  int bid = blockIdx.x;
  int t = threadIdx.x;
  if (bid < 4096) {
    int row = bid * 4 + (t >> 6);
    int lane = t & 63;
    const float4* xr = (const float4*)(hidden + (size_t)row * 512);
    float4 a = xr[lane];
    float4 b = xr[lane + 64];
    float s = a.x * a.x + a.y * a.y + a.z * a.z + a.w * a.w +
              b.x * b.x + b.y * b.y + b.z * b.z + b.w * b.w;
#pragma unroll
    for (int off = 32; off > 0; off >>= 1) s += __shfl_down(s, off, 64);
    float tot = __shfl(s, 0, 64);
    float rscale = rsqrtf(tot * (1.0f / 512.0f) + 1e-6f);
    float4 w0 = *(const float4*)(ln_w + 4 * lane);
    float4 w1 = *(const float4*)(ln_w + 256 + 4 * lane);
    bf16x4 o0, o1;
    o0[0] = (bf16)(a.x * rscale * w0.x);
    o0[1] = (bf16)(a.y * rscale * w0.y);
    o0[2] = (bf16)(a.z * rscale * w0.z);
    o0[3] = (bf16)(a.w * rscale * w0.w);
    o1[0] = (bf16)(b.x * rscale * w1.x);
    o1[1] = (bf16)(b.y * rscale * w1.y);
    o1[2] = (bf16)(b.z * rscale * w1.z);
    o1[3] = (bf16)(b.w * rscale * w1.w);
    *(bf16x4*)(normed + (size_t)row * 512 + 4 * lane) = o0;
    *(bf16x4*)(normed + (size_t)row * 512 + 256 + 4 * lane) = o1;
  } else if (bid < 4224) {
    int i = (bid - 4096) * 256 + t;  // 8 * 4096
    int h = i >> 12;
    int d = i & 4095;
    lut[(size_t)h * 4096 + d] = t5bias(table, h, d);
    if (i < 8) out_remain[i] = (float)i;
  } else if (bid < 5248) {
    int bid2 = bid - 4224;
    int mat = bid2 >> 8;
    int rem = bid2 & 255;
    int e0 = (rem & 15) * 32;
    int k0 = (rem >> 4) * 32;
    int tx = t & 31, ty = t >> 5;
    const float* W = (mat == 0) ? wq : (mat == 1) ? wk : (mat == 2) ? wv : wo;
#pragma unroll
    for (int j = 0; j < 32; j += 8)
      tile[ty + j][tx] = W[(size_t)(k0 + ty + j) * 512 + e0 + tx];
    __syncthreads();
    bf16* dst = (mat < 3) ? (wt_qkv + (size_t)mat * 512 * 512) : wt_o;
#pragma unroll
    for (int j = 0; j < 32; j += 8)
      dst[(size_t)(e0 + ty + j) * 512 + k0 + tx] = (bf16)tile[tx][ty + j];
  } else {
    int i = (bid - 5248) * 256 + t;  // 8 * 4096
    int h = i >> 12;
    int d = i & 4095;
    float4 o;
    o.x = t5bias(table, h, d) * LOG2E + NEG_SHIFT;
    o.y = t5bias(table, h, d + 1) * LOG2E + NEG_SHIFT;
    o.z = t5bias(table, h, d + 2) * LOG2E + NEG_SHIFT;
    o.w = t5bias(table, h, d + 3) * LOG2E + NEG_SHIFT;
    lutq[(size_t)h * 4096 + d] = o;
  }
}

// ---------------------------------------------------------------------------
// qkv GEMM: BK=64 (8 k-iters, halved barrier/drain count). [128][64] LDS
// tiles via glds direct; 1-bit both-sides XOR swizzle keeps ds_read_b128 at
// the 8-cycle bank floor: source col slot = (lane&7)^(((lane>>3)&1)<<2),
// read col slot = (s*4+quad)^((lc&1)<<2)  (write parity == read parity).
// Q is PRE-SCALED by LOG2E at store (folds the softmax fmaf into the GEMM).
// ---------------------------------------------------------------------------
__global__ __launch_bounds__(256) void qkv_gemm(
    const bf16* __restrict__ normed, const bf16* __restrict__ wt,
    bf16* __restrict__ qb, bf16* __restrict__ kb, bf16* __restrict__ vtb) {
  __shared__ __align__(16) char smem[32768];  // A [128][64] + B [128][64]
  bf16* As = (bf16*)smem;
  bf16* Bs = (bf16*)(smem + 16384);
  int t = threadIdx.x;
  int wave = t >> 6, lane = t & 63;
  int quad = lane >> 4, lc = lane & 15;
  int wm = wave >> 1, wn = wave & 1;
  int m0 = blockIdx.x * 128, n0 = blockIdx.y * 128;

  f32x4 acc[4][4];
#pragma unroll
  for (int i = 0; i < 4; i++)
#pragma unroll
    for (int j = 0; j < 4; j++) acc[i][j] = (f32x4){0.f, 0.f, 0.f, 0.f};

  int rw8 = lane >> 3;                             // row within 8-row group
  int cs = ((lane & 7) ^ ((rw8 & 1) << 2)) * 8;    // swizzled source col
  const bf16* gA = normed + (size_t)(m0 + wave * 32 + rw8) * 512 + cs;
  const bf16* gB = wt + (size_t)(n0 + wave * 32 + rw8) * 512 + cs;
  bf16* lA = As + wave * 2048;  // wave-uniform LDS base (32 rows x 64)
  bf16* lB = Bs + wave * 2048;

  for (int kt = 0; kt < 8; ++kt) {
    int k0 = kt * 64;
    __syncthreads();  // prev iter's frag reads done before overwrite
    glds16(gA + k0, lA);
    glds16(gA + 8 * 512 + k0, lA + 512);
    glds16(gA + 16 * 512 + k0, lA + 1024);
    glds16(gA + 24 * 512 + k0, lA + 1536);
    glds16(gB + k0, lB);
    glds16(gB + 8 * 512 + k0, lB + 512);
    glds16(gB + 16 * 512 + k0, lB + 1024);
    glds16(gB + 24 * 512 + k0, lB + 1536);
    __syncthreads();  // vmcnt(0) drain + barrier
#pragma unroll
    for (int s = 0; s < 2; ++s) {
      int colr = ((s * 4 + quad) ^ ((lc & 1) << 2)) * 8;  // de-swizzled read
      bf16x8 af[4], bfr[4];
#pragma unroll
      for (int i = 0; i < 4; i++)
        af[i] = *(const bf16x8*)&As[(wm * 64 + i * 16 + lc) * 64 + colr];
#pragma unroll
      for (int j = 0; j < 4; j++)
        bfr[j] = *(const bf16x8*)&Bs[(wn * 64 + j * 16 + lc) * 64 + colr];
#pragma unroll
      for (int i = 0; i < 4; i++)
#pragma unroll
        for (int j = 0; j < 4; j++)
          acc[i][j] = MFMA16(af[i], bfr[j], acc[i][j]);
    }
  }

  __syncthreads();  // all frag reads done before LDS reuse / epilogue
  int mat = n0 >> 9;
  int e_base = (n0 & 511) + wn * 64;
  int hh = e_base >> 6;
  int grow0 = m0 + wm * 64;
  int nbi = grow0 >> 11, sbase = grow0 & 2047;

  if (mat == 2) {
    // V: direct transposed stores vt[bh][d][s] (8B per store)
    bf16* dv = vtb + ((size_t)(nbi * 8 + hh) * 64) * 2048;
#pragma unroll
    for (int i = 0; i < 4; i++) {
      int s = sbase + i * 16 + quad * 4;
#pragma unroll
      for (int j = 0; j < 4; j++) {
        int d = j * 16 + lc;
        bf16x4 o4;
#pragma unroll
        for (int r = 0; r < 4; r++) o4[r] = (bf16)acc[i][j][r];
        *(bf16x4*)(dv + (size_t)d * 2048 + s) = o4;
      }
    }
  } else {
    float qsc = (mat == 0) ? LOG2E : 1.0f;  // pre-scale Q for exp2 softmax
    bf16* dst0 = (mat == 0) ? qb : kb;
    bf16* dst = dst0 + (((size_t)nbi * 8 + hh) * 2048 + sbase) * 64;
    bf16* Cw = (bf16*)smem + wave * 2432;  // 32x76 per wave
#pragma unroll
    for (int p = 0; p < 2; ++p) {
#pragma unroll
      for (int i2 = 0; i2 < 2; ++i2) {
#pragma unroll
        for (int j = 0; j < 4; ++j)
#pragma unroll
          for (int r = 0; r < 4; ++r)
            Cw[(i2 * 16 + quad * 4 + r) * 76 + j * 16 + lc] =
                (bf16)(acc[2 * p + i2][j][r] * qsc);
      }
      // wave-local write->read; compiler inserts lgkmcnt wait
#pragma unroll
      for (int c = 0; c < 4; ++c) {
        bf16x8 vch =
            *(const bf16x8*)&Cw[(c * 8 + (lane >> 3)) * 76 + (lane & 7) * 8];
        *(bf16x8*)(dst + (size_t)(p * 32 + c * 8 + (lane >> 3)) * 64 +
                   (lane & 7) * 8) = vch;
      }
    }
  }
}

// ---------------------------------------------------------------------------
// attn: blocks [0,1024) = flash attention (R9-proven: reg-staged K/V,
// [64][72] padded LDS, dbuf, 1 barrier/tile, (256,3) so st/O stay
// VGPR-class -- no v_accvgpr round-trips); blocks [1024,33792) = bias.
// ---------------------------------------------------------------------------
#define LDB4(SV, G, V4)       \
  {                           \
    float4 _b = (V4);         \
    SV[4 * (G) + 0] = _b.x;   \
    SV[4 * (G) + 1] = _b.y;   \
    SV[4 * (G) + 2] = _b.z;   \
    SV[4 * (G) + 3] = _b.w;   \
  }

__global__ __launch_bounds__(256, 3) void attn_kernel(
    const bf16* __restrict__ qg, const bf16* __restrict__ kg,
    const bf16* __restrict__ vtg, const float4* __restrict__ lutq,
    const float* __restrict__ lut, bf16* __restrict__ ctx,
    float* __restrict__ bias_out) {
  __shared__ bf16 Ks[2][64][72];  // 2 x 9216 B, double-buffered
  __shared__ bf16 Vs[2][64][72];
  int t = threadIdx.x;

  if (blockIdx.x >= 1024) {  // ---- bias path (R0-proven) ----
    size_t i = (((size_t)blockIdx.x - 1024) * 256 + t) * 4;
    int h = (int)(i >> 22);
    int q = (int)((i >> 11) & 2047);
    int k = (int)(i & 2047);
    const float* lh = lut + (size_t)h * 4096 + (2047 - q);
    float4 v = {lh[k], lh[k + 1], lh[k + 2], lh[k + 3]};
    *(float4*)(bias_out + i) = v;
    return;
  }

  // ---- attention path ----
  int id = blockIdx.x;
  int xcd = id & 7, slot = id >> 3;  // XCD-aware: each XCD owns 8 whole bh
  int bh = xcd * 8 + (slot >> 4);
  int qt = slot & 15;
  int n = bh >> 3, h = bh & 7;
  int q0 = qt * 128;

  int wave = t >> 6, lane = t & 63;
  int l31 = lane & 31, hi = lane >> 5;
  int q = q0 + wave * 32 + l31;

  // bias base for this lane (lutq is pre-scaled: LOG2E*bias + NEG_SHIFT)
  const float4* bp = lutq + (size_t)h * 4096 + (2047 + 4 * hi - q);

  // Q fragments: B[k=d][n=q], pre-scaled by LOG2E (L2-hot)
  const bf16* qp = qg + ((size_t)bh * 2048 + q) * 64;
  bf16x8 Qf[4];
#pragma unroll
  for (int c = 0; c < 4; c++) Qf[c] = *(const bf16x8*)(qp + c * 16 + hi * 8);

  f32x16 O[2];
#pragma unroll
  for (int i = 0; i < 2; i++)
#pragma unroll
    for (int e = 0; e < 16; e++) O[i][e] = 0.f;
  f32x2 lsA = {0.f, 0.f}, lsB = {0.f, 0.f};

  int srow = t >> 2, scol = (t & 3) * 16;
  const bf16* kp = kg + (size_t)bh * 2048 * 64 + (size_t)srow * 64 + scol;
  const bf16* vp = vtg + (size_t)bh * 64 * 2048 + (size_t)srow * 2048 + scol;

  // prologue: stage tile 0 -> buf 0
  {
    bf16x8 a0 = *(const bf16x8*)(kp);
    bf16x8 a1 = *(const bf16x8*)(kp + 8);
    bf16x8 a2 = *(const bf16x8*)(vp);
    bf16x8 a3 = *(const bf16x8*)(vp + 8);
    *(bf16x8*)&Ks[0][srow][scol] = a0;
    *(bf16x8*)&Ks[0][srow][scol + 8] = a1;
    *(bf16x8*)&Vs[0][srow][scol] = a2;
    *(bf16x8*)&Vs[0][srow][scol + 8] = a3;
  }
  // bias tile 0 -> st (MFMA C-operand)
  f32x16 st[2];
  LDB4(st[0], 0, bp[0]);
  LDB4(st[0], 1, bp[8]);
  LDB4(st[0], 2, bp[16]);
  LDB4(st[0], 3, bp[24]);
  LDB4(st[1], 0, bp[32]);
  LDB4(st[1], 1, bp[40]);
  LDB4(st[1], 2, bp[48]);
  LDB4(st[1], 3, bp[56]);
  const float4* bpn = bp + 64;
  __syncthreads();

#pragma unroll 1
  for (int kt = 0; kt < 32; ++kt) {
    int RB = kt & 1;
    bool pf = (kt < 31);
    bf16x8 kv0, kv1, vv0, vv1;
    if (pf) {  // prefetch next K/V tile into registers
      const bf16* kn = kp + (size_t)(kt + 1) * 4096;
      const bf16* vn = vp + (kt + 1) * 64;
      kv0 = *(const bf16x8*)(kn);
      kv1 = *(const bf16x8*)(kn + 8);
      vv0 = *(const bf16x8*)(vn);
      vv1 = *(const bf16x8*)(vn + 8);
    }

#pragma unroll
    for (int mi = 0; mi < 2; mi++) {
      const bf16* krow = &Ks[RB][mi * 32 + l31][hi * 8];
      bf16x8 kf0 = *(const bf16x8*)(krow);
      bf16x8 kf1 = *(const bf16x8*)(krow + 16);
      bf16x8 kf2 = *(const bf16x8*)(krow + 32);
      bf16x8 kf3 = *(const bf16x8*)(krow + 48);
      __builtin_amdgcn_s_setprio(1);
      st[mi] = MFMA32(kf0, Qf[0], st[mi]);
      st[mi] = MFMA32(kf1, Qf[1], st[mi]);
      st[mi] = MFMA32(kf2, Qf[2], st[mi]);
      st[mi] = MFMA32(kf3, Qf[3], st[mi]);
      __builtin_amdgcn_s_setprio(0);

      unsigned D[8];
#pragma unroll
      for (int g = 0; g < 4; g++) {
#pragma unroll
        for (int e = 0; e < 4; e++)
          st[mi][4 * g + e] = __builtin_amdgcn_exp2f(st[mi][4 * g + e]);
        lsA += (f32x2){st[mi][4 * g + 0], st[mi][4 * g + 1]};
        lsB += (f32x2){st[mi][4 * g + 2], st[mi][4 * g + 3]};
        D[2 * g] = pkbf(st[mi][4 * g + 0], st[mi][4 * g + 1]);
        D[2 * g + 1] = pkbf(st[mi][4 * g + 2], st[mi][4 * g + 3]);
      }
      if (pf) {  // st[mi] dead after pack: reload next tile's bias
        LDB4(st[mi], 0, bpn[mi * 32 + 0]);
        LDB4(st[mi], 1, bpn[mi * 32 + 8]);
        LDB4(st[mi], 2, bpn[mi * 32 + 16]);
        LDB4(st[mi], 3, bpn[mi * 32 + 24]);
      }
      pl32swap(D[0], D[2]);
      pl32swap(D[1], D[3]);
      pl32swap(D[4], D[6]);
      pl32swap(D[5], D[7]);
      union { uint4 u; bf16x8 v; } cv0, cv1;
      cv0.u = make_uint4(D[0], D[1], D[2], D[3]);
      cv1.u = make_uint4(D[4], D[5], D[6], D[7]);
#pragma unroll
      for (int kk = 0; kk < 2; kk++) {
        int kc = 2 * mi + kk;
        const bf16* vrow = &Vs[RB][l31][kc * 16 + hi * 8];
        bf16x8 vf0 = *(const bf16x8*)(vrow);
        bf16x8 vf1 = *(const bf16x8*)(vrow + 32 * 72);
        bf16x8 pfv = kk ? cv1.v : cv0.v;
        __builtin_amdgcn_s_setprio(1);
        O[0] = MFMA32(vf0, pfv, O[0]);
        O[1] = MFMA32(vf1, pfv, O[1]);
        __builtin_amdgcn_s_setprio(0);
      }
    }

    if (pf) {
      int WB = RB ^ 1;
      *(bf16x8*)&Ks[WB][srow][scol] = kv0;
      *(bf16x8*)&Ks[WB][srow][scol + 8] = kv1;
      *(bf16x8*)&Vs[WB][srow][scol] = vv0;
      *(bf16x8*)&Vs[WB][srow][scol + 8] = vv1;
      bpn += 64;
    }
    __syncthreads();
  }

  float l_run = lsA.x + lsA.y + lsB.x + lsB.y;
  l_run += __shfl_xor(l_run, 32, 64);
  float inv = 1.0f / l_run;
  bf16* cp = ctx + ((size_t)n * 2048 + q) * 512 + h * 64;
#pragma unroll
  for (int md = 0; md < 2; md++)
#pragma unroll
    for (int g = 0; g < 4; g++) {
      bf16x4 o4;
#pragma unroll
      for (int e = 0; e < 4; e++) o4[e] = (bf16)(O[md][4 * g + e] * inv);
      *(bf16x4*)(cp + md * 32 + 8 * g + hi * 4) = o4;
    }
}

// ---------------------------------------------------------------------------
// oproj: out = ctx @ wo + hidden (residual), fp32 out. BK=64 (8 k-iters)
// with the same 1-bit both-sides swizzle as qkv.
// ---------------------------------------------------------------------------
__global__ __launch_bounds__(256) void oproj_gemm(
    const bf16* __restrict__ ctx, const bf16* __restrict__ wt_o,
    const float* __restrict__ hidden, float* __restrict__ out) {
  __shared__ __align__(16) char smem[32768];
  bf16* As = (bf16*)smem;
  bf16* Bs = (bf16*)(smem + 16384);
  int t = threadIdx.x;
  int wave = t >> 6, lane = t & 63;
  int quad = lane >> 4, lc = lane & 15;
  int wm = wave >> 1, wn = wave & 1;
  int m0 = blockIdx.x * 128, n0 = blockIdx.y * 128;

  f32x4 acc[4][4];
#pragma unroll
  for (int i = 0; i < 4; i++)
#pragma unroll
    for (int j = 0; j < 4; j++) acc[i][j] = (f32x4){0.f, 0.f, 0.f, 0.f};

  int rw8 = lane >> 3;
  int cs = ((lane & 7) ^ ((rw8 & 1) << 2)) * 8;
  const bf16* gA = ctx + (size_t)(m0 + wave * 32 + rw8) * 512 + cs;
  const bf16* gB = wt_o + (size_t)(n0 + wave * 32 + rw8) * 512 + cs;
  bf16* lA = As + wave * 2048;
  bf16* lB = Bs + wave * 2048;

  for (int kt = 0; kt < 8; ++kt) {
    int k0 = kt * 64;
    __syncthreads();
    glds16(gA + k0, lA);
    glds16(gA + 8 * 512 + k0, lA + 512);
    glds16(gA + 16 * 512 + k0, lA + 1024);
    glds16(gA + 24 * 512 + k0, lA + 1536);
    glds16(gB + k0, lB);
    glds16(gB + 8 * 512 + k0, lB + 512);
    glds16(gB + 16 * 512 + k0, lB + 1024);
    glds16(gB + 24 * 512 + k0, lB + 1536);
    __syncthreads();
#pragma unroll
    for (int s = 0; s < 2; ++s) {
      int colr = ((s * 4 + quad) ^ ((lc & 1) << 2)) * 8;
      bf16x8 af[4], bfr[4];
#pragma unroll
      for (int i = 0; i < 4; i++)
        af[i] = *(const bf16x8*)&As[(wm * 64 + i * 16 + lc) * 64 + colr];
#pragma unroll
      for (int j = 0; j < 4; j++)
        bfr[j] = *(const bf16x8*)&Bs[(wn * 64 + j * 16 + lc) * 64 + colr];
#pragma unroll
      for (int i = 0; i < 4; i++)
#pragma unroll
        for (int j = 0; j < 4; j++)
          acc[i][j] = MFMA16(af[i], bfr[j], acc[i][j]);
    }
  }

#pragma unroll
  for (int i = 0; i < 4; i++) {
#pragma unroll
    for (int j = 0; j < 4; j++) {
#pragma unroll
      for (int r = 0; r < 4; r++) {
        int grow = m0 + wm * 64 + i * 16 + quad * 4 + r;
        int gcol = n0 + wn * 64 + j * 16 + lc;
        size_t idx = (size_t)grow * 512 + gcol;
        out[idx] = acc[i][j][r] + hidden[idx];
      }
    }
  }
}

// ---------------------------------------------------------------------------
extern "C" void kernel_launch(void* const* d_in, const int* in_sizes, int n_in,
                              void* d_out, int out_size, void* d_ws, size_t ws_size,
                              hipStream_t stream) {
  const float* hidden = (const float*)d_in[0];
  const float* ln_w = (const float*)d_in[1];
  const float* wq = (const float*)d_in[2];
  const float* wk = (const float*)d_in[3];
  const float* wv = (const float*)d_in[4];
  const float* wo = (const float*)d_in[5];
  const float* table = (const float*)d_in[6];

  float* out_hidden = (float*)d_out;                       // 8*2048*512
  float* out_bias = out_hidden + (size_t)8 * 2048 * 512;   // 8*2048*2048
  float* out_remain = out_bias + (size_t)8 * 2048 * 2048;  // 8

  char* ws = (char*)d_ws;
  bf16* normed = (bf16*)(ws + 0);            // 16 MiB (reused as ctx later)
  float* lut = (float*)(ws + 16777216);      // 128 KiB
  float4* lutq = (float4*)(ws + 16908288);   // 512 KiB
  bf16* wt_qkv = (bf16*)(ws + 17432576);     // 1.5 MiB
  bf16* wt_o = (bf16*)(ws + 19005440);       // 0.5 MiB
  bf16* qb = (bf16*)(ws + 19529728);         // 16 MiB each
  bf16* kb = qb + (size_t)8 * 8 * 2048 * 64;
  bf16* vtb = kb + (size_t)8 * 8 * 2048 * 64;
  bf16* ctx = normed;  // alias: normed consumed by qkv before attn writes ctx

  prep_kernel<<<dim3(5376), dim3(256), 0, stream>>>(
      hidden, ln_w, wq, wk, wv, wo, table, normed, lut, lutq, out_remain,
      wt_qkv, wt_o);
  qkv_gemm<<<dim3(128, 12), dim3(256), 0, stream>>>(normed, wt_qkv, qb, kb, vtb);
  attn_kernel<<<dim3(1024 + 32768), dim3(256), 0, stream>>>(
      qb, kb, vtb, lutq, lut, ctx, out_bias);
  oproj_gemm<<<dim3(128, 4), dim3(256), 0, stream>>>(ctx, wt_o, hidden,
                                                     out_hidden);
}